// Round 5
// baseline (338.228 us; speedup 1.0000x reference)
//
#include <hip/hip_runtime.h>
#include <cstdint>
#include <cstddef>

// ---------- types ----------
typedef __attribute__((ext_vector_type(8))) short  bf16x8;   // MFMA bf16 A/B frag (K=32)
typedef __attribute__((ext_vector_type(4))) _Float16 f16x4;  // MFMA f16 A/B frag (K=16)
typedef __attribute__((ext_vector_type(4))) float  f32x4;    // MFMA C/D frag
typedef __attribute__((ext_vector_type(4))) unsigned short u16x4;
typedef __attribute__((ext_vector_type(2))) unsigned int u32x2;

#define LOG2E 1.44269504088896340736f
#define PBIAS 6.0f   // softmax shift (cancels in normalization); keeps 2^t in f16 range

__device__ __forceinline__ unsigned short f2bf(float f) {
  unsigned int u = __builtin_bit_cast(unsigned int, f);
  u += 0x7fffu + ((u >> 16) & 1u);
  return (unsigned short)(u >> 16);
}
__device__ __forceinline__ float bf2f(unsigned short s) {
  unsigned int u = ((unsigned int)s) << 16;
  return __builtin_bit_cast(float, u);
}

// async global->LDS, 16B per lane (wave-uniform LDS base + lane*16)
__device__ __forceinline__ void gll16(const void* g, void* l) {
  __builtin_amdgcn_global_load_lds(
      (const __attribute__((address_space(1))) unsigned int*)g,
      (__attribute__((address_space(3))) unsigned int*)l, 16, 0, 0);
}

// ---------- fused converts ----------
__global__ void cvt2(const float* __restrict__ s0, unsigned short* __restrict__ d0, int n40,
                     const float* __restrict__ s1, unsigned short* __restrict__ d1, int n41) {
  const float* s = blockIdx.y ? s1 : s0;
  unsigned short* d = blockIdx.y ? d1 : d0;
  int n4 = blockIdx.y ? n41 : n40;
  int i = blockIdx.x * blockDim.x + threadIdx.x;
  if (i < n4) {
    float4 v = ((const float4*)s)[i];
    u16x4 o;
    o[0] = f2bf(v.x); o[1] = f2bf(v.y); o[2] = f2bf(v.z); o[3] = f2bf(v.w);
    ((u16x4*)d)[i] = o;
  }
}

// ---------- batched transpose fp32(1024x1024) -> bf16 transposed ----------
__global__ void tr4(const float* __restrict__ s0, const float* __restrict__ s1,
                    const float* __restrict__ s2, const float* __restrict__ s3,
                    unsigned short* __restrict__ d0, unsigned short* __restrict__ d1,
                    unsigned short* __restrict__ d2, unsigned short* __restrict__ d3) {
  int z = blockIdx.z;
  const float* in = z == 0 ? s0 : (z == 1 ? s1 : (z == 2 ? s2 : s3));
  unsigned short* out = z == 0 ? d0 : (z == 1 ? d1 : (z == 2 ? d2 : d3));
  __shared__ unsigned short s[64][68];
  int t = threadIdx.x;
  int r0 = blockIdx.y * 64, c0 = blockIdx.x * 64;
  int tr = t >> 4, tc4 = (t & 15) * 4;
  for (int i = 0; i < 4; ++i) {
    int r = tr + i * 16;
    float4 v = *(const float4*)(in + (size_t)(r0 + r) * 1024 + c0 + tc4);
    s[r][tc4 + 0] = f2bf(v.x); s[r][tc4 + 1] = f2bf(v.y);
    s[r][tc4 + 2] = f2bf(v.z); s[r][tc4 + 3] = f2bf(v.w);
  }
  __syncthreads();
  for (int i = 0; i < 4; ++i) {
    int oc = tr + i * 16;
    u16x4 o;
    o[0] = s[tc4 + 0][oc]; o[1] = s[tc4 + 1][oc];
    o[2] = s[tc4 + 2][oc]; o[3] = s[tc4 + 3][oc];
    *(u16x4*)(out + (size_t)(c0 + oc) * 1024 + r0 + tc4) = o;
  }
}

// ---------- transpose V: bf16 [4096][1024] -> f16 [1024][4096] ----------
__global__ void tr_v(const unsigned short* __restrict__ in, unsigned short* __restrict__ out) {
  __shared__ unsigned short s[64][68];
  int t = threadIdx.x;
  int r0 = blockIdx.y * 64, c0 = blockIdx.x * 64;
  int tr = t >> 4, tc4 = (t & 15) * 4;
  for (int i = 0; i < 4; ++i) {
    int r = tr + i * 16;
    u16x4 v = *(const u16x4*)(in + (size_t)(r0 + r) * 1024 + c0 + tc4);
    s[r][tc4 + 0] = v[0]; s[r][tc4 + 1] = v[1]; s[r][tc4 + 2] = v[2]; s[r][tc4 + 3] = v[3];
  }
  __syncthreads();
  for (int i = 0; i < 4; ++i) {
    int oc = tr + i * 16;
    u16x4 o;
#pragma unroll
    for (int j = 0; j < 4; ++j) {
      _Float16 h = (_Float16)bf2f(s[tc4 + j][oc]);
      o[j] = __builtin_bit_cast(unsigned short, h);
    }
    *(u16x4*)(out + (size_t)(c0 + oc) * 4096 + r0 + tc4) = o;
  }
}

// ---------- NT GEMM: C[M][N] = A[M][K]*B[N][K]^T, 128x128 tile, BK=64, XOR-swizzled LDS ----------
template <bool BF16OUT>
__global__ __launch_bounds__(256) void gemm_nt(
    const unsigned short* __restrict__ A,
    const unsigned short* __restrict__ B0, const unsigned short* __restrict__ B1,
    const unsigned short* __restrict__ B2,
    void* __restrict__ C0, void* __restrict__ C1, void* __restrict__ C2,
    int M, int N, int K) {
  const unsigned short* B = blockIdx.z == 0 ? B0 : (blockIdx.z == 1 ? B1 : B2);
  void* Cv = blockIdx.z == 0 ? C0 : (blockIdx.z == 1 ? C1 : C2);

  __shared__ unsigned short As[128 * 64];
  __shared__ unsigned short Bs[128 * 64];

  int tid = threadIdx.x, w = tid >> 6, lane = tid & 63;
  int lo = lane & 15, quad = lane >> 4;
  int m0 = blockIdx.y * 128, n0 = blockIdx.x * 128;
  int wm = (w >> 1) * 64, wn = (w & 1) * 64;

  f32x4 z4 = {0.f, 0.f, 0.f, 0.f};
  f32x4 acc[4][4];
  for (int mi = 0; mi < 4; ++mi)
    for (int ni = 0; ni < 4; ++ni) acc[mi][ni] = z4;

  int rloc = lane >> 3;
  int srcChunk = (lane & 7) ^ (rloc & 7);
  int cbase = w * 4;
  const unsigned short* Ag = A + (size_t)(m0 + cbase * 8 + rloc) * K + srcChunk * 8;
  const unsigned short* Bg = B + (size_t)(n0 + cbase * 8 + rloc) * K + srcChunk * 8;
  int ldsOfs = cbase * 512 + lane * 8;
  int cx0 = (quad ^ (lane & 7)) * 8;
  int cx1 = ((quad + 4) ^ (lane & 7)) * 8;

  for (int k0 = 0; k0 < K; k0 += 64) {
#pragma unroll
    for (int j = 0; j < 4; ++j) {
      gll16(Ag + (size_t)j * 8 * K + k0, As + ldsOfs + j * 512);
      gll16(Bg + (size_t)j * 8 * K + k0, Bs + ldsOfs + j * 512);
    }
    __syncthreads();
#pragma unroll
    for (int ks = 0; ks < 2; ++ks) {
      int cx = ks ? cx1 : cx0;
      bf16x8 af[4], bfr[4];
#pragma unroll
      for (int mi = 0; mi < 4; ++mi)
        af[mi] = *(const bf16x8*)(As + (wm + mi * 16 + lo) * 64 + cx);
#pragma unroll
      for (int ni = 0; ni < 4; ++ni)
        bfr[ni] = *(const bf16x8*)(Bs + (wn + ni * 16 + lo) * 64 + cx);
#pragma unroll
      for (int mi = 0; mi < 4; ++mi)
#pragma unroll
        for (int ni = 0; ni < 4; ++ni)
          acc[mi][ni] = __builtin_amdgcn_mfma_f32_16x16x32_bf16(af[mi], bfr[ni], acc[mi][ni], 0, 0, 0);
    }
    __syncthreads();
  }

#pragma unroll
  for (int mi = 0; mi < 4; ++mi)
#pragma unroll
    for (int ni = 0; ni < 4; ++ni)
      for (int i = 0; i < 4; ++i) {
        int r = m0 + wm + mi * 16 + quad * 4 + i;
        int c = n0 + wn + ni * 16 + lo;
        if (BF16OUT)
          ((unsigned short*)Cv)[(size_t)r * N + c] = f2bf(acc[mi][ni][i]);
        else
          ((float*)Cv)[(size_t)r * N + c] = acc[mi][ni][i];
      }
}

// ---------- flash attention v3: LDS-free, barrier-free, register-pipelined ----------
// Q,K: bf16 [4096][1024]; Vt: f16 [1024][4096]; O: bf16 [4096][1024].
// 1 wave per block (64 thr), 32 q-rows/wave, KV tiles of 64.
// All fragments loaded straight from global in MFMA layout; K prefetched one tile ahead.
__global__ __launch_bounds__(64) void flash_attn(
    const unsigned short* __restrict__ Q, const unsigned short* __restrict__ Kg_,
    const unsigned short* __restrict__ Vt, const float* __restrict__ ent,
    unsigned short* __restrict__ O) {
  int lane = threadIdx.x;
  int lo = lane & 15, quad = lane >> 4;
  int b = blockIdx.y >> 4, h = blockIdx.y & 15;
  int q0 = blockIdx.x * 32;
  float scale = ent[h] * (0.125f * LOG2E);

  // Q fragments (B-operand of S^T), scale folded in.
  bf16x8 aq[2][2];
#pragma unroll
  for (int t = 0; t < 2; ++t)
#pragma unroll
    for (int ks = 0; ks < 2; ++ks) {
      uint4 v = *(const uint4*)(Q + (size_t)(b * 2048 + q0 + t * 16 + lo) * 1024 +
                                h * 64 + ks * 32 + quad * 8);
      unsigned int* pv = (unsigned int*)&v;
      uint4 o; unsigned int* po = (unsigned int*)&o;
#pragma unroll
      for (int j = 0; j < 4; ++j) {
        float f0 = bf2f((unsigned short)(pv[j] & 0xffffu)) * scale;
        float f1 = bf2f((unsigned short)(pv[j] >> 16)) * scale;
        po[j] = (unsigned int)f2bf(f0) | ((unsigned int)f2bf(f1) << 16);
      }
      aq[t][ks] = *(bf16x8*)&o;
    }

  const unsigned short* Kp = Kg_ + (size_t)(b * 2048) * 1024 + h * 64;
  const unsigned short* Vp = Vt + (size_t)(h * 64) * 4096 + (size_t)b * 2048;

  f32x4 binit = {-PBIAS, -PBIAS, -PBIAS, -PBIAS};
  f32x4 z4 = {0.f, 0.f, 0.f, 0.f};
  f32x4 acco[2][4];
#pragma unroll
  for (int t = 0; t < 2; ++t)
    for (int di = 0; di < 4; ++di) acco[t][di] = z4;
  float lsum[2] = {0.f, 0.f};

  // K A-fragments for tile 0 (register-resident, prefetched across tiles)
  bf16x8 kf[4][2];
#pragma unroll
  for (int kt = 0; kt < 4; ++kt)
#pragma unroll
    for (int ks = 0; ks < 2; ++ks)
      kf[kt][ks] = *(const bf16x8*)(Kp + (size_t)(kt * 16 + lo) * 1024 + ks * 32 + quad * 8);

  for (int kv0 = 0; kv0 < 2048; kv0 += 64) {
    // V B-fragments for this tile (issued early; covered by the QK^T MFMAs)
    f16x4 vf[4][4];
#pragma unroll
    for (int kt = 0; kt < 4; ++kt)
#pragma unroll
      for (int di = 0; di < 4; ++di)
        vf[kt][di] = *(const f16x4*)(Vp + (size_t)(di * 16 + lo) * 4096 +
                                     kv0 + kt * 16 + quad * 4);

    // S^T = K.Q^T : C[m=kv][n=q]; bias -PBIAS folded into the C-init (free)
    f32x4 accs[2][4];
#pragma unroll
    for (int kt = 0; kt < 4; ++kt)
#pragma unroll
      for (int t = 0; t < 2; ++t) {
        f32x4 a = __builtin_amdgcn_mfma_f32_16x16x32_bf16(kf[kt][0], aq[t][0], binit, 0, 0, 0);
        accs[t][kt] = __builtin_amdgcn_mfma_f32_16x16x32_bf16(kf[kt][1], aq[t][1], a, 0, 0, 0);
      }

    // prefetch next K tile (lands during exp + PV)
    int kvn = kv0 + 64;
    if (kvn < 2048) {
#pragma unroll
      for (int kt = 0; kt < 4; ++kt)
#pragma unroll
        for (int ks = 0; ks < 2; ++ks)
          kf[kt][ks] = *(const bf16x8*)(Kp + (size_t)(kvn + kt * 16 + lo) * 1024 +
                                        ks * 32 + quad * 8);
    }

    // P' = 2^(S^T - bias): registers hold P[q=lo][kv] == f16 A-frag layout (K=16)
    f16x4 ap[2][4];
#pragma unroll
    for (int t = 0; t < 2; ++t)
#pragma unroll
      for (int kt = 0; kt < 4; ++kt) {
        float p0 = exp2f(accs[t][kt][0]);
        float p1 = exp2f(accs[t][kt][1]);
        float p2 = exp2f(accs[t][kt][2]);
        float p3 = exp2f(accs[t][kt][3]);
        lsum[t] += (p0 + p1) + (p2 + p3);
        u32x2 uu;
        uu[0] = __builtin_bit_cast(unsigned int, __builtin_amdgcn_cvt_pkrtz(p0, p1));
        uu[1] = __builtin_bit_cast(unsigned int, __builtin_amdgcn_cvt_pkrtz(p2, p3));
        ap[t][kt] = __builtin_bit_cast(f16x4, uu);
      }

    // O += P.V via f16 16x16x16 MFMA, all operands in registers
#pragma unroll
    for (int kt = 0; kt < 4; ++kt)
#pragma unroll
      for (int di = 0; di < 4; ++di) {
        acco[0][di] = __builtin_amdgcn_mfma_f32_16x16x16f16(ap[0][kt], vf[kt][di], acco[0][di], 0, 0, 0);
        acco[1][di] = __builtin_amdgcn_mfma_f32_16x16x16f16(ap[1][kt], vf[kt][di], acco[1][di], 0, 0, 0);
      }
  }

  // row sums live per-lane at q=lo, spread over quads -> 2 shuffles
  float inv[2];
#pragma unroll
  for (int t = 0; t < 2; ++t) {
    float v = lsum[t];
    v += __shfl_xor(v, 16);
    v += __shfl_xor(v, 32);
    inv[t] = 1.0f / v;
  }
  // O is C-layout (row=q=quad*4+i, col=d=di*16+lo)
#pragma unroll
  for (int t = 0; t < 2; ++t)
#pragma unroll
    for (int i = 0; i < 4; ++i) {
      float invq = __shfl(inv[t], quad * 4 + i);
#pragma unroll
      for (int di = 0; di < 4; ++di) {
        size_t ofs = (size_t)(b * 2048 + q0 + t * 16 + quad * 4 + i) * 1024 +
                     h * 64 + di * 16 + lo;
        O[ofs] = f2bf(acco[t][di][i] * invq);
      }
    }
}

// ---------- launch ----------
extern "C" void kernel_launch(void* const* d_in, const int* in_sizes, int n_in,
                              void* d_out, int out_size, void* d_ws, size_t ws_size,
                              hipStream_t stream) {
  const float* x   = (const float*)d_in[0];
  const float* R   = (const float*)d_in[1];
  const float* ent = (const float*)d_in[2];
  const float* Wq  = (const float*)d_in[3];
  const float* Wk  = (const float*)d_in[4];
  const float* Wv  = (const float*)d_in[5];
  const float* Wo  = (const float*)d_in[6];
  float* out = (float*)d_out;

  const size_t MLD = (size_t)4096 * 1024;
  const size_t DD  = (size_t)1024 * 1024;
  if (ws_size < (MLD * 6 + DD * 8) * 2) return;

  unsigned short* ws  = (unsigned short*)d_ws;
  unsigned short* xb  = ws;
  unsigned short* RT  = xb + MLD;
  unsigned short* WqT = RT + DD;
  unsigned short* WkT = WqT + DD;
  unsigned short* WvT = WkT + DD;
  unsigned short* Wob = WvT + DD;
  unsigned short* AqT = Wob + DD;
  unsigned short* AkT = AqT + DD;
  unsigned short* AvT = AkT + DD;
  unsigned short* Qb  = AvT + DD;
  unsigned short* Kb  = Qb + MLD;
  unsigned short* Vb  = Kb + MLD;
  unsigned short* Vtf = Vb + MLD;   // V^T as f16 [1024][4096]
  unsigned short* aO  = Vtf + MLD;

  cvt2<<<dim3(4096, 2), dim3(256), 0, stream>>>(
      x, xb, (int)(MLD / 4), Wo, Wob, (int)(DD / 4));
  tr4<<<dim3(16, 16, 4), dim3(256), 0, stream>>>(R, Wq, Wk, Wv, RT, WqT, WkT, WvT);

  // A*T = NT(RT, W*T) = R^T W* = (W*^T R)^T
  gemm_nt<true><<<dim3(8, 8, 3), dim3(256), 0, stream>>>(
      RT, WqT, WkT, WvT, (void*)AqT, (void*)AkT, (void*)AvT, 1024, 1024, 1024);
  // Q/K/V = NT(xb, A*T)
  gemm_nt<true><<<dim3(8, 32, 3), dim3(256), 0, stream>>>(
      xb, AqT, AkT, AvT, (void*)Qb, (void*)Kb, (void*)Vb, 4096, 1024, 1024);
  // V -> V^T (f16)
  tr_v<<<dim3(16, 64), dim3(256), 0, stream>>>(Vb, Vtf);
  // attention (LDS-free)
  flash_attn<<<dim3(64, 32), dim3(64), 0, stream>>>(Qb, Kb, Vtf, ent, aO);
  // out = NT(aO, Wob) -> fp32
  gemm_nt<false><<<dim3(8, 32, 1), dim3(256), 0, stream>>>(
      aO, Wob, Wob, Wob, (void*)out, (void*)out, (void*)out, 4096, 1024, 1024);
}

// Round 6
// 256.311 us; speedup vs baseline: 1.3196x; 1.3196x over previous
//
#include <hip/hip_runtime.h>
#include <cstdint>
#include <cstddef>

// ---------- types ----------
typedef __attribute__((ext_vector_type(8))) short  bf16x8;   // MFMA bf16 A/B frag (K=32)
typedef __attribute__((ext_vector_type(4))) _Float16 f16x4;  // MFMA f16 A/B frag (K=16)
typedef __attribute__((ext_vector_type(4))) float  f32x4;    // MFMA C/D frag
typedef __attribute__((ext_vector_type(4))) unsigned short u16x4;
typedef __attribute__((ext_vector_type(2))) unsigned int u32x2;

#define LOG2E 1.44269504088896340736f
#define PBIAS 6.0f   // softmax shift (cancels in normalization); keeps 2^t in f16 range

__device__ __forceinline__ unsigned short f2bf(float f) {
  unsigned int u = __builtin_bit_cast(unsigned int, f);
  u += 0x7fffu + ((u >> 16) & 1u);
  return (unsigned short)(u >> 16);
}
__device__ __forceinline__ float bf2f(unsigned short s) {
  unsigned int u = ((unsigned int)s) << 16;
  return __builtin_bit_cast(float, u);
}

// async global->LDS, 16B per lane (wave-uniform LDS base + lane*16)
__device__ __forceinline__ void gll16(const void* g, void* l) {
  __builtin_amdgcn_global_load_lds(
      (const __attribute__((address_space(1))) unsigned int*)g,
      (__attribute__((address_space(3))) unsigned int*)l, 16, 0, 0);
}

// ---------- fused converts ----------
__global__ void cvt2(const float* __restrict__ s0, unsigned short* __restrict__ d0, int n40,
                     const float* __restrict__ s1, unsigned short* __restrict__ d1, int n41) {
  const float* s = blockIdx.y ? s1 : s0;
  unsigned short* d = blockIdx.y ? d1 : d0;
  int n4 = blockIdx.y ? n41 : n40;
  int i = blockIdx.x * blockDim.x + threadIdx.x;
  if (i < n4) {
    float4 v = ((const float4*)s)[i];
    u16x4 o;
    o[0] = f2bf(v.x); o[1] = f2bf(v.y); o[2] = f2bf(v.z); o[3] = f2bf(v.w);
    ((u16x4*)d)[i] = o;
  }
}

// ---------- batched transpose fp32(1024x1024) -> bf16 transposed ----------
__global__ void tr4(const float* __restrict__ s0, const float* __restrict__ s1,
                    const float* __restrict__ s2, const float* __restrict__ s3,
                    unsigned short* __restrict__ d0, unsigned short* __restrict__ d1,
                    unsigned short* __restrict__ d2, unsigned short* __restrict__ d3) {
  int z = blockIdx.z;
  const float* in = z == 0 ? s0 : (z == 1 ? s1 : (z == 2 ? s2 : s3));
  unsigned short* out = z == 0 ? d0 : (z == 1 ? d1 : (z == 2 ? d2 : d3));
  __shared__ unsigned short s[64][68];
  int t = threadIdx.x;
  int r0 = blockIdx.y * 64, c0 = blockIdx.x * 64;
  int tr = t >> 4, tc4 = (t & 15) * 4;
  for (int i = 0; i < 4; ++i) {
    int r = tr + i * 16;
    float4 v = *(const float4*)(in + (size_t)(r0 + r) * 1024 + c0 + tc4);
    s[r][tc4 + 0] = f2bf(v.x); s[r][tc4 + 1] = f2bf(v.y);
    s[r][tc4 + 2] = f2bf(v.z); s[r][tc4 + 3] = f2bf(v.w);
  }
  __syncthreads();
  for (int i = 0; i < 4; ++i) {
    int oc = tr + i * 16;
    u16x4 o;
    o[0] = s[tc4 + 0][oc]; o[1] = s[tc4 + 1][oc];
    o[2] = s[tc4 + 2][oc]; o[3] = s[tc4 + 3][oc];
    *(u16x4*)(out + (size_t)(c0 + oc) * 1024 + r0 + tc4) = o;
  }
}

// ---------- transpose V: bf16 [4096][1024] -> f16 [1024][4096] ----------
__global__ void tr_v(const unsigned short* __restrict__ in, unsigned short* __restrict__ out) {
  __shared__ unsigned short s[64][68];
  int t = threadIdx.x;
  int r0 = blockIdx.y * 64, c0 = blockIdx.x * 64;
  int tr = t >> 4, tc4 = (t & 15) * 4;
  for (int i = 0; i < 4; ++i) {
    int r = tr + i * 16;
    u16x4 v = *(const u16x4*)(in + (size_t)(r0 + r) * 1024 + c0 + tc4);
    s[r][tc4 + 0] = v[0]; s[r][tc4 + 1] = v[1]; s[r][tc4 + 2] = v[2]; s[r][tc4 + 3] = v[3];
  }
  __syncthreads();
  for (int i = 0; i < 4; ++i) {
    int oc = tr + i * 16;
    u16x4 o;
#pragma unroll
    for (int j = 0; j < 4; ++j) {
      _Float16 h = (_Float16)bf2f(s[tc4 + j][oc]);
      o[j] = __builtin_bit_cast(unsigned short, h);
    }
    *(u16x4*)(out + (size_t)(c0 + oc) * 4096 + r0 + tc4) = o;
  }
}

// ---------- NT GEMM: C[M][N] = A[M][K]*B[N][K]^T, 128x128 tile, BK=64, XOR-swizzled LDS ----------
template <bool BF16OUT>
__global__ __launch_bounds__(256) void gemm_nt(
    const unsigned short* __restrict__ A,
    const unsigned short* __restrict__ B0, const unsigned short* __restrict__ B1,
    const unsigned short* __restrict__ B2,
    void* __restrict__ C0, void* __restrict__ C1, void* __restrict__ C2,
    int M, int N, int K) {
  const unsigned short* B = blockIdx.z == 0 ? B0 : (blockIdx.z == 1 ? B1 : B2);
  void* Cv = blockIdx.z == 0 ? C0 : (blockIdx.z == 1 ? C1 : C2);

  __shared__ unsigned short As[128 * 64];
  __shared__ unsigned short Bs[128 * 64];

  int tid = threadIdx.x, w = tid >> 6, lane = tid & 63;
  int lo = lane & 15, quad = lane >> 4;
  int m0 = blockIdx.y * 128, n0 = blockIdx.x * 128;
  int wm = (w >> 1) * 64, wn = (w & 1) * 64;

  f32x4 z4 = {0.f, 0.f, 0.f, 0.f};
  f32x4 acc[4][4];
  for (int mi = 0; mi < 4; ++mi)
    for (int ni = 0; ni < 4; ++ni) acc[mi][ni] = z4;

  int rloc = lane >> 3;
  int srcChunk = (lane & 7) ^ (rloc & 7);
  int cbase = w * 4;
  const unsigned short* Ag = A + (size_t)(m0 + cbase * 8 + rloc) * K + srcChunk * 8;
  const unsigned short* Bg = B + (size_t)(n0 + cbase * 8 + rloc) * K + srcChunk * 8;
  int ldsOfs = cbase * 512 + lane * 8;
  int cx0 = (quad ^ (lane & 7)) * 8;
  int cx1 = ((quad + 4) ^ (lane & 7)) * 8;

  for (int k0 = 0; k0 < K; k0 += 64) {
#pragma unroll
    for (int j = 0; j < 4; ++j) {
      gll16(Ag + (size_t)j * 8 * K + k0, As + ldsOfs + j * 512);
      gll16(Bg + (size_t)j * 8 * K + k0, Bs + ldsOfs + j * 512);
    }
    __syncthreads();
#pragma unroll
    for (int ks = 0; ks < 2; ++ks) {
      int cx = ks ? cx1 : cx0;
      bf16x8 af[4], bfr[4];
#pragma unroll
      for (int mi = 0; mi < 4; ++mi)
        af[mi] = *(const bf16x8*)(As + (wm + mi * 16 + lo) * 64 + cx);
#pragma unroll
      for (int ni = 0; ni < 4; ++ni)
        bfr[ni] = *(const bf16x8*)(Bs + (wn + ni * 16 + lo) * 64 + cx);
#pragma unroll
      for (int mi = 0; mi < 4; ++mi)
#pragma unroll
        for (int ni = 0; ni < 4; ++ni)
          acc[mi][ni] = __builtin_amdgcn_mfma_f32_16x16x32_bf16(af[mi], bfr[ni], acc[mi][ni], 0, 0, 0);
    }
    __syncthreads();
  }

#pragma unroll
  for (int mi = 0; mi < 4; ++mi)
#pragma unroll
    for (int ni = 0; ni < 4; ++ni)
      for (int i = 0; i < 4; ++i) {
        int r = m0 + wm + mi * 16 + quad * 4 + i;
        int c = n0 + wn + ni * 16 + lo;
        if (BF16OUT)
          ((unsigned short*)Cv)[(size_t)r * N + c] = f2bf(acc[mi][ni][i]);
        else
          ((float*)Cv)[(size_t)r * N + c] = acc[mi][ni][i];
      }
}

// ---------- flash attention v6: LDS double-buffer, prefetch-after-barrier ----------
// Q,K: bf16 [4096][1024]; Vt: f16 [1024][4096]; O: bf16 [4096][1024].
// Block = 128 threads (2 waves) x 64 q-rows; KV tiles of 64; XOR-swizzled LDS.
// One barrier per tile: barrier drains the PREVIOUS iteration's prefetch (which had a
// full tile of compute to land), then next tile's staging is issued, then compute.
__global__ __launch_bounds__(128) void flash_attn(
    const unsigned short* __restrict__ Q, const unsigned short* __restrict__ Kg_,
    const unsigned short* __restrict__ Vt, const float* __restrict__ ent,
    unsigned short* __restrict__ O) {
  int tid = threadIdx.x, w = tid >> 6, lane = tid & 63;
  int lo = lane & 15, quad = lane >> 4;
  int b = blockIdx.y >> 4, h = blockIdx.y & 15;
  int q0 = blockIdx.x * 64;
  float scale = ent[h] * (0.125f * LOG2E);

  __shared__ unsigned short Ks[2][64 * 64];
  __shared__ unsigned short Vts[2][64 * 64];   // f16 bits, [d][l], swizzled

  // Q fragments (B-operand of S^T) straight from global, scale folded in.
  bf16x8 aq[2][2];
#pragma unroll
  for (int t = 0; t < 2; ++t)
#pragma unroll
    for (int ks = 0; ks < 2; ++ks) {
      uint4 v = *(const uint4*)(Q + (size_t)(b * 2048 + q0 + w * 32 + t * 16 + lo) * 1024 +
                                h * 64 + ks * 32 + quad * 8);
      unsigned int* pv = (unsigned int*)&v;
      uint4 o; unsigned int* po = (unsigned int*)&o;
#pragma unroll
      for (int j = 0; j < 4; ++j) {
        float f0 = bf2f((unsigned short)(pv[j] & 0xffffu)) * scale;
        float f1 = bf2f((unsigned short)(pv[j] >> 16)) * scale;
        po[j] = (unsigned int)f2bf(f0) | ((unsigned int)f2bf(f1) << 16);
      }
      aq[t][ks] = *(bf16x8*)&o;
    }

  f32x4 binit = {-PBIAS, -PBIAS, -PBIAS, -PBIAS};
  f32x4 z4 = {0.f, 0.f, 0.f, 0.f};
  f32x4 acco[2][4];
#pragma unroll
  for (int t = 0; t < 2; ++t)
    for (int di = 0; di < 4; ++di) acco[t][di] = z4;
  float lsum[2] = {0.f, 0.f};

  int rloc = lane >> 3;
  int srcChunk = (lane & 7) ^ (rloc & 7);
  int cb = w * 4;
  const unsigned short* Kp = Kg_ + (size_t)(b * 2048) * 1024 + h * 64;
  const unsigned short* Vp = Vt + (size_t)(h * 64) * 4096 + (size_t)b * 2048;
  int cx0 = (quad ^ (lane & 7)) * 8;
  int cx1 = ((quad + 4) ^ (lane & 7)) * 8;

  // stage tile 0 into buffer 0
#pragma unroll
  for (int j = 0; j < 4; ++j) {
    int c = cb + j;
    int r = c * 8 + rloc;
    gll16(Kp + (size_t)r * 1024 + srcChunk * 8, Ks[0] + c * 512 + lane * 8);
    gll16(Vp + (size_t)r * 4096 + srcChunk * 8, Vts[0] + c * 512 + lane * 8);
  }

  for (int it = 0; it < 32; ++it) {
    int buf = it & 1;
    // drains this tile's staging (issued one full tile ago) + protects buf^1 reuse
    __syncthreads();
    if (it + 1 < 32) {
      int kvn = (it + 1) * 64;
#pragma unroll
      for (int j = 0; j < 4; ++j) {
        int c = cb + j;
        int r = c * 8 + rloc;
        gll16(Kp + (size_t)(kvn + r) * 1024 + srcChunk * 8, Ks[buf ^ 1] + c * 512 + lane * 8);
        gll16(Vp + (size_t)r * 4096 + kvn + srcChunk * 8, Vts[buf ^ 1] + c * 512 + lane * 8);
      }
    }
    const unsigned short* Kb_ = Ks[buf];
    const unsigned short* Vb_ = Vts[buf];

    // S^T = K.Q^T : C[m=kv][n=q]; bias -PBIAS folded into the C-init (free)
    f32x4 accs[2][4];
#pragma unroll
    for (int kt = 0; kt < 4; ++kt) {
      bf16x8 kf0 = *(const bf16x8*)(Kb_ + (kt * 16 + lo) * 64 + cx0);
      bf16x8 kf1 = *(const bf16x8*)(Kb_ + (kt * 16 + lo) * 64 + cx1);
#pragma unroll
      for (int t = 0; t < 2; ++t) {
        f32x4 a = __builtin_amdgcn_mfma_f32_16x16x32_bf16(kf0, aq[t][0], binit, 0, 0, 0);
        accs[t][kt] = __builtin_amdgcn_mfma_f32_16x16x32_bf16(kf1, aq[t][1], a, 0, 0, 0);
      }
    }

    // P' = 2^(S^T - bias): registers hold P[q=lo][kv] == f16 A-frag layout (K=16)
    f16x4 ap[2][4];
#pragma unroll
    for (int t = 0; t < 2; ++t)
#pragma unroll
      for (int kt = 0; kt < 4; ++kt) {
        float p0 = exp2f(accs[t][kt][0]);
        float p1 = exp2f(accs[t][kt][1]);
        float p2 = exp2f(accs[t][kt][2]);
        float p3 = exp2f(accs[t][kt][3]);
        lsum[t] += (p0 + p1) + (p2 + p3);
        u32x2 uu;
        uu[0] = __builtin_bit_cast(unsigned int, __builtin_amdgcn_cvt_pkrtz(p0, p1));
        uu[1] = __builtin_bit_cast(unsigned int, __builtin_amdgcn_cvt_pkrtz(p2, p3));
        ap[t][kt] = __builtin_bit_cast(f16x4, uu);
      }

    // O += P.V via f16 16x16x16 MFMA; B-frag from swizzled Vts (ds_read_b64)
#pragma unroll
    for (int kt = 0; kt < 4; ++kt)
#pragma unroll
      for (int di = 0; di < 4; ++di) {
        f16x4 bv = *(const f16x4*)(Vb_ + (di * 16 + lo) * 64 +
                                   (((kt * 2 + (quad >> 1)) ^ (lo & 7)) << 3) + ((quad & 1) << 2));
        acco[0][di] = __builtin_amdgcn_mfma_f32_16x16x16f16(ap[0][kt], bv, acco[0][di], 0, 0, 0);
        acco[1][di] = __builtin_amdgcn_mfma_f32_16x16x16f16(ap[1][kt], bv, acco[1][di], 0, 0, 0);
      }
  }

  // row sums live per-lane at q=lo, spread over quads -> 2 shuffles
  float inv[2];
#pragma unroll
  for (int t = 0; t < 2; ++t) {
    float v = lsum[t];
    v += __shfl_xor(v, 16);
    v += __shfl_xor(v, 32);
    inv[t] = 1.0f / v;
  }
  // O is C-layout (row=q=quad*4+i, col=d=di*16+lo); fetch inv for q=quad*4+i via shuffle
#pragma unroll
  for (int t = 0; t < 2; ++t)
#pragma unroll
    for (int i = 0; i < 4; ++i) {
      float invq = __shfl(inv[t], quad * 4 + i);
#pragma unroll
      for (int di = 0; di < 4; ++di) {
        size_t ofs = (size_t)(b * 2048 + q0 + w * 32 + t * 16 + quad * 4 + i) * 1024 +
                     h * 64 + di * 16 + lo;
        O[ofs] = f2bf(acco[t][di][i] * invq);
      }
    }
}

// ---------- launch ----------
extern "C" void kernel_launch(void* const* d_in, const int* in_sizes, int n_in,
                              void* d_out, int out_size, void* d_ws, size_t ws_size,
                              hipStream_t stream) {
  const float* x   = (const float*)d_in[0];
  const float* R   = (const float*)d_in[1];
  const float* ent = (const float*)d_in[2];
  const float* Wq  = (const float*)d_in[3];
  const float* Wk  = (const float*)d_in[4];
  const float* Wv  = (const float*)d_in[5];
  const float* Wo  = (const float*)d_in[6];
  float* out = (float*)d_out;

  const size_t MLD = (size_t)4096 * 1024;
  const size_t DD  = (size_t)1024 * 1024;
  if (ws_size < (MLD * 6 + DD * 8) * 2) return;

  unsigned short* ws  = (unsigned short*)d_ws;
  unsigned short* xb  = ws;
  unsigned short* RT  = xb + MLD;
  unsigned short* WqT = RT + DD;
  unsigned short* WkT = WqT + DD;
  unsigned short* WvT = WkT + DD;
  unsigned short* Wob = WvT + DD;
  unsigned short* AqT = Wob + DD;
  unsigned short* AkT = AqT + DD;
  unsigned short* AvT = AkT + DD;
  unsigned short* Qb  = AvT + DD;
  unsigned short* Kb  = Qb + MLD;
  unsigned short* Vb  = Kb + MLD;
  unsigned short* Vtf = Vb + MLD;   // V^T as f16 [1024][4096]
  unsigned short* aO  = Vtf + MLD;

  cvt2<<<dim3(4096, 2), dim3(256), 0, stream>>>(
      x, xb, (int)(MLD / 4), Wo, Wob, (int)(DD / 4));
  tr4<<<dim3(16, 16, 4), dim3(256), 0, stream>>>(R, Wq, Wk, Wv, RT, WqT, WkT, WvT);

  // A*T = NT(RT, W*T) = R^T W* = (W*^T R)^T
  gemm_nt<true><<<dim3(8, 8, 3), dim3(256), 0, stream>>>(
      RT, WqT, WkT, WvT, (void*)AqT, (void*)AkT, (void*)AvT, 1024, 1024, 1024);
  // Q/K/V = NT(xb, A*T)
  gemm_nt<true><<<dim3(8, 32, 3), dim3(256), 0, stream>>>(
      xb, AqT, AkT, AvT, (void*)Qb, (void*)Kb, (void*)Vb, 4096, 1024, 1024);
  // V -> V^T (f16)
  tr_v<<<dim3(16, 64), dim3(256), 0, stream>>>(Vb, Vtf);
  // attention (double-buffered)
  flash_attn<<<dim3(32, 32), dim3(128), 0, stream>>>(Qb, Kb, Vtf, ent, aO);
  // out = NT(aO, Wob) -> fp32
  gemm_nt<false><<<dim3(8, 32, 1), dim3(256), 0, stream>>>(
      aO, Wob, Wob, Wob, (void*)out, (void*)out, (void*)out, 4096, 1024, 1024);
}

// Round 7
// 241.018 us; speedup vs baseline: 1.4033x; 1.0635x over previous
//
#include <hip/hip_runtime.h>
#include <cstdint>
#include <cstddef>

// ---------- types ----------
typedef __attribute__((ext_vector_type(8))) short  bf16x8;   // MFMA bf16 A/B frag (K=32)
typedef __attribute__((ext_vector_type(4))) _Float16 f16x4;  // MFMA f16 A/B frag (K=16)
typedef __attribute__((ext_vector_type(4))) float  f32x4;    // MFMA C/D frag
typedef __attribute__((ext_vector_type(4))) unsigned short u16x4;
typedef __attribute__((ext_vector_type(2))) unsigned int u32x2;

#define LOG2E 1.44269504088896340736f
#define PBIAS 6.0f   // softmax shift (cancels in normalization); keeps 2^t in f16 range

__device__ __forceinline__ unsigned short f2bf(float f) {
  unsigned int u = __builtin_bit_cast(unsigned int, f);
  u += 0x7fffu + ((u >> 16) & 1u);
  return (unsigned short)(u >> 16);
}
__device__ __forceinline__ float bf2f(unsigned short s) {
  unsigned int u = ((unsigned int)s) << 16;
  return __builtin_bit_cast(float, u);
}

// async global->LDS, 16B per lane (wave-uniform LDS base + lane*16)
__device__ __forceinline__ void gll16(const void* g, void* l) {
  __builtin_amdgcn_global_load_lds(
      (const __attribute__((address_space(1))) unsigned int*)g,
      (__attribute__((address_space(3))) unsigned int*)l, 16, 0, 0);
}

// ---------- fused converts ----------
__global__ void cvt2(const float* __restrict__ s0, unsigned short* __restrict__ d0, int n40,
                     const float* __restrict__ s1, unsigned short* __restrict__ d1, int n41) {
  const float* s = blockIdx.y ? s1 : s0;
  unsigned short* d = blockIdx.y ? d1 : d0;
  int n4 = blockIdx.y ? n41 : n40;
  int i = blockIdx.x * blockDim.x + threadIdx.x;
  if (i < n4) {
    float4 v = ((const float4*)s)[i];
    u16x4 o;
    o[0] = f2bf(v.x); o[1] = f2bf(v.y); o[2] = f2bf(v.z); o[3] = f2bf(v.w);
    ((u16x4*)d)[i] = o;
  }
}

// ---------- batched transpose fp32(1024x1024) -> bf16 transposed ----------
__global__ void tr4(const float* __restrict__ s0, const float* __restrict__ s1,
                    const float* __restrict__ s2, const float* __restrict__ s3,
                    unsigned short* __restrict__ d0, unsigned short* __restrict__ d1,
                    unsigned short* __restrict__ d2, unsigned short* __restrict__ d3) {
  int z = blockIdx.z;
  const float* in = z == 0 ? s0 : (z == 1 ? s1 : (z == 2 ? s2 : s3));
  unsigned short* out = z == 0 ? d0 : (z == 1 ? d1 : (z == 2 ? d2 : d3));
  __shared__ unsigned short s[64][68];
  int t = threadIdx.x;
  int r0 = blockIdx.y * 64, c0 = blockIdx.x * 64;
  int tr = t >> 4, tc4 = (t & 15) * 4;
  for (int i = 0; i < 4; ++i) {
    int r = tr + i * 16;
    float4 v = *(const float4*)(in + (size_t)(r0 + r) * 1024 + c0 + tc4);
    s[r][tc4 + 0] = f2bf(v.x); s[r][tc4 + 1] = f2bf(v.y);
    s[r][tc4 + 2] = f2bf(v.z); s[r][tc4 + 3] = f2bf(v.w);
  }
  __syncthreads();
  for (int i = 0; i < 4; ++i) {
    int oc = tr + i * 16;
    u16x4 o;
    o[0] = s[tc4 + 0][oc]; o[1] = s[tc4 + 1][oc];
    o[2] = s[tc4 + 2][oc]; o[3] = s[tc4 + 3][oc];
    *(u16x4*)(out + (size_t)(c0 + oc) * 1024 + r0 + tc4) = o;
  }
}

// ---------- transpose V: bf16 [4096][1024] -> f16 [1024][4096] ----------
__global__ void tr_v(const unsigned short* __restrict__ in, unsigned short* __restrict__ out) {
  __shared__ unsigned short s[64][68];
  int t = threadIdx.x;
  int r0 = blockIdx.y * 64, c0 = blockIdx.x * 64;
  int tr = t >> 4, tc4 = (t & 15) * 4;
  for (int i = 0; i < 4; ++i) {
    int r = tr + i * 16;
    u16x4 v = *(const u16x4*)(in + (size_t)(r0 + r) * 1024 + c0 + tc4);
    s[r][tc4 + 0] = v[0]; s[r][tc4 + 1] = v[1]; s[r][tc4 + 2] = v[2]; s[r][tc4 + 3] = v[3];
  }
  __syncthreads();
  for (int i = 0; i < 4; ++i) {
    int oc = tr + i * 16;
    u16x4 o;
#pragma unroll
    for (int j = 0; j < 4; ++j) {
      _Float16 h = (_Float16)bf2f(s[tc4 + j][oc]);
      o[j] = __builtin_bit_cast(unsigned short, h);
    }
    *(u16x4*)(out + (size_t)(c0 + oc) * 4096 + r0 + tc4) = o;
  }
}

// ---------- NT GEMM: C[M][N] = A[M][K]*B[N][K]^T, 128x128 tile, BK=64, XOR-swizzled LDS ----------
template <bool BF16OUT>
__global__ __launch_bounds__(256) void gemm_nt(
    const unsigned short* __restrict__ A,
    const unsigned short* __restrict__ B0, const unsigned short* __restrict__ B1,
    const unsigned short* __restrict__ B2,
    void* __restrict__ C0, void* __restrict__ C1, void* __restrict__ C2,
    int M, int N, int K) {
  const unsigned short* B = blockIdx.z == 0 ? B0 : (blockIdx.z == 1 ? B1 : B2);
  void* Cv = blockIdx.z == 0 ? C0 : (blockIdx.z == 1 ? C1 : C2);

  __shared__ unsigned short As[128 * 64];
  __shared__ unsigned short Bs[128 * 64];

  int tid = threadIdx.x, w = tid >> 6, lane = tid & 63;
  int lo = lane & 15, quad = lane >> 4;
  int m0 = blockIdx.y * 128, n0 = blockIdx.x * 128;
  int wm = (w >> 1) * 64, wn = (w & 1) * 64;

  f32x4 z4 = {0.f, 0.f, 0.f, 0.f};
  f32x4 acc[4][4];
  for (int mi = 0; mi < 4; ++mi)
    for (int ni = 0; ni < 4; ++ni) acc[mi][ni] = z4;

  int rloc = lane >> 3;
  int srcChunk = (lane & 7) ^ (rloc & 7);
  int cbase = w * 4;
  const unsigned short* Ag = A + (size_t)(m0 + cbase * 8 + rloc) * K + srcChunk * 8;
  const unsigned short* Bg = B + (size_t)(n0 + cbase * 8 + rloc) * K + srcChunk * 8;
  int ldsOfs = cbase * 512 + lane * 8;
  int cx0 = (quad ^ (lane & 7)) * 8;
  int cx1 = ((quad + 4) ^ (lane & 7)) * 8;

  for (int k0 = 0; k0 < K; k0 += 64) {
#pragma unroll
    for (int j = 0; j < 4; ++j) {
      gll16(Ag + (size_t)j * 8 * K + k0, As + ldsOfs + j * 512);
      gll16(Bg + (size_t)j * 8 * K + k0, Bs + ldsOfs + j * 512);
    }
    __syncthreads();
#pragma unroll
    for (int ks = 0; ks < 2; ++ks) {
      int cx = ks ? cx1 : cx0;
      bf16x8 af[4], bfr[4];
#pragma unroll
      for (int mi = 0; mi < 4; ++mi)
        af[mi] = *(const bf16x8*)(As + (wm + mi * 16 + lo) * 64 + cx);
#pragma unroll
      for (int ni = 0; ni < 4; ++ni)
        bfr[ni] = *(const bf16x8*)(Bs + (wn + ni * 16 + lo) * 64 + cx);
#pragma unroll
      for (int mi = 0; mi < 4; ++mi)
#pragma unroll
        for (int ni = 0; ni < 4; ++ni)
          acc[mi][ni] = __builtin_amdgcn_mfma_f32_16x16x32_bf16(af[mi], bfr[ni], acc[mi][ni], 0, 0, 0);
    }
    __syncthreads();
  }

#pragma unroll
  for (int mi = 0; mi < 4; ++mi)
#pragma unroll
    for (int ni = 0; ni < 4; ++ni)
      for (int i = 0; i < 4; ++i) {
        int r = m0 + wm + mi * 16 + quad * 4 + i;
        int c = n0 + wn + ni * 16 + lo;
        if (BF16OUT)
          ((unsigned short*)Cv)[(size_t)r * N + c] = f2bf(acc[mi][ni][i]);
        else
          ((float*)Cv)[(size_t)r * N + c] = acc[mi][ni][i];
      }
}

// ---------- flash attention v7: 4 waves/block, 16 q/wave, XCD-local grouping ----------
// Q,K: bf16 [4096][1024]; Vt: f16 [1024][4096]; O: bf16 [4096][1024].
// 1D grid of 1024 blocks, 256 thr. Block id encodes (b,h) group with id%8 fixed per
// group so all 32 q-tiles of one (b,h) land on one XCD (L2-local K/V stream).
// Single barrier per KV tile; LDS double-buffer with prefetch-after-barrier.
__global__ __launch_bounds__(256) void flash_attn(
    const unsigned short* __restrict__ Q, const unsigned short* __restrict__ Kg_,
    const unsigned short* __restrict__ Vt, const float* __restrict__ ent,
    unsigned short* __restrict__ O) {
  int tid = threadIdx.x, w = tid >> 6, lane = tid & 63;
  int lo = lane & 15, quad = lane >> 4;

  int bid = blockIdx.x;
  int g = (bid & 7) + 8 * (bid >> 8);        // (b,h) group: id%8 fixed per group
  int qt = (bid >> 3) & 31;                  // q-tile within group
  int b = g >> 4, h = g & 15;
  int q0 = qt * 64;
  float scale = ent[h] * (0.125f * LOG2E);

  __shared__ unsigned short Ks[2][64 * 64];
  __shared__ unsigned short Vts[2][64 * 64];   // f16 bits, [d][l], swizzled

  // Q fragments (B-operand of S^T) straight from global, scale folded in. 16 q rows/wave.
  bf16x8 aq[2];
#pragma unroll
  for (int ks = 0; ks < 2; ++ks) {
    uint4 v = *(const uint4*)(Q + (size_t)(b * 2048 + q0 + w * 16 + lo) * 1024 +
                              h * 64 + ks * 32 + quad * 8);
    unsigned int* pv = (unsigned int*)&v;
    uint4 o; unsigned int* po = (unsigned int*)&o;
#pragma unroll
    for (int j = 0; j < 4; ++j) {
      float f0 = bf2f((unsigned short)(pv[j] & 0xffffu)) * scale;
      float f1 = bf2f((unsigned short)(pv[j] >> 16)) * scale;
      po[j] = (unsigned int)f2bf(f0) | ((unsigned int)f2bf(f1) << 16);
    }
    aq[ks] = *(bf16x8*)&o;
  }

  f32x4 binit = {-PBIAS, -PBIAS, -PBIAS, -PBIAS};
  f32x4 z4 = {0.f, 0.f, 0.f, 0.f};
  f32x4 acco[4];
#pragma unroll
  for (int di = 0; di < 4; ++di) acco[di] = z4;
  float lsum = 0.f;

  int rloc = lane >> 3;
  int srcChunk = (lane & 7) ^ (rloc & 7);
  int cb = w * 2;                            // 4 waves cover 8 chunks per matrix
  const unsigned short* Kp = Kg_ + (size_t)(b * 2048) * 1024 + h * 64;
  const unsigned short* Vp = Vt + (size_t)(h * 64) * 4096 + (size_t)b * 2048;
  int cx0 = (quad ^ (lane & 7)) * 8;
  int cx1 = ((quad + 4) ^ (lane & 7)) * 8;

  // stage tile 0 into buffer 0
#pragma unroll
  for (int j = 0; j < 2; ++j) {
    int c = cb + j;
    int r = c * 8 + rloc;
    gll16(Kp + (size_t)r * 1024 + srcChunk * 8, Ks[0] + c * 512 + lane * 8);
    gll16(Vp + (size_t)r * 4096 + srcChunk * 8, Vts[0] + c * 512 + lane * 8);
  }

  for (int it = 0; it < 32; ++it) {
    int buf = it & 1;
    __syncthreads();   // drains this tile's staging (issued one full tile ago)
    if (it + 1 < 32) {
      int kvn = (it + 1) * 64;
#pragma unroll
      for (int j = 0; j < 2; ++j) {
        int c = cb + j;
        int r = c * 8 + rloc;
        gll16(Kp + (size_t)(kvn + r) * 1024 + srcChunk * 8, Ks[buf ^ 1] + c * 512 + lane * 8);
        gll16(Vp + (size_t)r * 4096 + kvn + srcChunk * 8, Vts[buf ^ 1] + c * 512 + lane * 8);
      }
    }
    const unsigned short* Kb_ = Ks[buf];
    const unsigned short* Vb_ = Vts[buf];

    // S^T = K.Q^T : C[m=kv][n=q]; bias -PBIAS folded into the C-init (free)
    f32x4 accs[4];
#pragma unroll
    for (int kt = 0; kt < 4; ++kt) {
      bf16x8 kf0 = *(const bf16x8*)(Kb_ + (kt * 16 + lo) * 64 + cx0);
      bf16x8 kf1 = *(const bf16x8*)(Kb_ + (kt * 16 + lo) * 64 + cx1);
      f32x4 a = __builtin_amdgcn_mfma_f32_16x16x32_bf16(kf0, aq[0], binit, 0, 0, 0);
      accs[kt] = __builtin_amdgcn_mfma_f32_16x16x32_bf16(kf1, aq[1], a, 0, 0, 0);
    }

    // P' = 2^(S^T - bias): registers hold P[q=lo][kv] == f16 A-frag layout (K=16)
    f16x4 ap[4];
#pragma unroll
    for (int kt = 0; kt < 4; ++kt) {
      float p0 = exp2f(accs[kt][0]);
      float p1 = exp2f(accs[kt][1]);
      float p2 = exp2f(accs[kt][2]);
      float p3 = exp2f(accs[kt][3]);
      lsum += (p0 + p1) + (p2 + p3);
      u32x2 uu;
      uu[0] = __builtin_bit_cast(unsigned int, __builtin_amdgcn_cvt_pkrtz(p0, p1));
      uu[1] = __builtin_bit_cast(unsigned int, __builtin_amdgcn_cvt_pkrtz(p2, p3));
      ap[kt] = __builtin_bit_cast(f16x4, uu);
    }

    // O += P.V via f16 16x16x16 MFMA; B-frag from swizzled Vts (ds_read_b64)
#pragma unroll
    for (int kt = 0; kt < 4; ++kt)
#pragma unroll
      for (int di = 0; di < 4; ++di) {
        f16x4 bv = *(const f16x4*)(Vb_ + (di * 16 + lo) * 64 +
                                   (((kt * 2 + (quad >> 1)) ^ (lo & 7)) << 3) + ((quad & 1) << 2));
        acco[di] = __builtin_amdgcn_mfma_f32_16x16x16f16(ap[kt], bv, acco[di], 0, 0, 0);
      }
  }

  // row sum for q=lo spread over quads -> 2 shuffles
  float v = lsum;
  v += __shfl_xor(v, 16);
  v += __shfl_xor(v, 32);
  float inv = 1.0f / v;

  // O is C-layout (row=q=quad*4+i, col=d=di*16+lo); fetch inv for q=quad*4+i via shuffle
#pragma unroll
  for (int i = 0; i < 4; ++i) {
    float invq = __shfl(inv, quad * 4 + i);
#pragma unroll
    for (int di = 0; di < 4; ++di) {
      size_t ofs = (size_t)(b * 2048 + q0 + w * 16 + quad * 4 + i) * 1024 +
                   h * 64 + di * 16 + lo;
      O[ofs] = f2bf(acco[di][i] * invq);
    }
  }
}

// ---------- launch ----------
extern "C" void kernel_launch(void* const* d_in, const int* in_sizes, int n_in,
                              void* d_out, int out_size, void* d_ws, size_t ws_size,
                              hipStream_t stream) {
  const float* x   = (const float*)d_in[0];
  const float* R   = (const float*)d_in[1];
  const float* ent = (const float*)d_in[2];
  const float* Wq  = (const float*)d_in[3];
  const float* Wk  = (const float*)d_in[4];
  const float* Wv  = (const float*)d_in[5];
  const float* Wo  = (const float*)d_in[6];
  float* out = (float*)d_out;

  const size_t MLD = (size_t)4096 * 1024;
  const size_t DD  = (size_t)1024 * 1024;
  if (ws_size < (MLD * 6 + DD * 8) * 2) return;

  unsigned short* ws  = (unsigned short*)d_ws;
  unsigned short* xb  = ws;
  unsigned short* RT  = xb + MLD;
  unsigned short* WqT = RT + DD;
  unsigned short* WkT = WqT + DD;
  unsigned short* WvT = WkT + DD;
  unsigned short* Wob = WvT + DD;
  unsigned short* AqT = Wob + DD;
  unsigned short* AkT = AqT + DD;
  unsigned short* AvT = AkT + DD;
  unsigned short* Qb  = AvT + DD;
  unsigned short* Kb  = Qb + MLD;
  unsigned short* Vb  = Kb + MLD;
  unsigned short* Vtf = Vb + MLD;   // V^T as f16 [1024][4096]
  unsigned short* aO  = Vtf + MLD;

  cvt2<<<dim3(4096, 2), dim3(256), 0, stream>>>(
      x, xb, (int)(MLD / 4), Wo, Wob, (int)(DD / 4));
  tr4<<<dim3(16, 16, 4), dim3(256), 0, stream>>>(R, Wq, Wk, Wv, RT, WqT, WkT, WvT);

  // A*T = NT(RT, W*T) = R^T W* = (W*^T R)^T
  gemm_nt<true><<<dim3(8, 8, 3), dim3(256), 0, stream>>>(
      RT, WqT, WkT, WvT, (void*)AqT, (void*)AkT, (void*)AvT, 1024, 1024, 1024);
  // Q/K/V = NT(xb, A*T)
  gemm_nt<true><<<dim3(8, 32, 3), dim3(256), 0, stream>>>(
      xb, AqT, AkT, AvT, (void*)Qb, (void*)Kb, (void*)Vb, 4096, 1024, 1024);
  // V -> V^T (f16)
  tr_v<<<dim3(16, 64), dim3(256), 0, stream>>>(Vb, Vtf);
  // attention (4 waves/block, XCD-local)
  flash_attn<<<dim3(1024), dim3(256), 0, stream>>>(Qb, Kb, Vtf, ent, aO);
  // out = NT(aO, Wob) -> fp32
  gemm_nt<false><<<dim3(8, 32, 1), dim3(256), 0, stream>>>(
      aO, Wob, Wob, Wob, (void*)out, (void*)out, (void*)out, 4096, 1024, 1024);
}

// Round 8
// 234.065 us; speedup vs baseline: 1.4450x; 1.0297x over previous
//
#include <hip/hip_runtime.h>
#include <cstdint>
#include <cstddef>

// ---------- types ----------
typedef __attribute__((ext_vector_type(8))) short  bf16x8;   // MFMA bf16 A/B frag (K=32)
typedef __attribute__((ext_vector_type(8))) _Float16 f16x8;  // 16B LDS read (2 f16 B-frags)
typedef __attribute__((ext_vector_type(4))) _Float16 f16x4;  // MFMA f16 A/B frag (K=16)
typedef __attribute__((ext_vector_type(4))) float  f32x4;    // MFMA C/D frag
typedef __attribute__((ext_vector_type(4))) unsigned short u16x4;
typedef __attribute__((ext_vector_type(2))) unsigned int u32x2;

#define LOG2E 1.44269504088896340736f
#define PBIAS 6.0f   // softmax shift (cancels in normalization); keeps 2^t in f16 range

__device__ __forceinline__ unsigned short f2bf(float f) {
  unsigned int u = __builtin_bit_cast(unsigned int, f);
  u += 0x7fffu + ((u >> 16) & 1u);
  return (unsigned short)(u >> 16);
}
__device__ __forceinline__ float bf2f(unsigned short s) {
  unsigned int u = ((unsigned int)s) << 16;
  return __builtin_bit_cast(float, u);
}

// async global->LDS, 16B per lane (wave-uniform LDS base + lane*16)
__device__ __forceinline__ void gll16(const void* g, void* l) {
  __builtin_amdgcn_global_load_lds(
      (const __attribute__((address_space(1))) unsigned int*)g,
      (__attribute__((address_space(3))) unsigned int*)l, 16, 0, 0);
}

// ---------- fused converts ----------
__global__ void cvt2(const float* __restrict__ s0, unsigned short* __restrict__ d0, int n40,
                     const float* __restrict__ s1, unsigned short* __restrict__ d1, int n41) {
  const float* s = blockIdx.y ? s1 : s0;
  unsigned short* d = blockIdx.y ? d1 : d0;
  int n4 = blockIdx.y ? n41 : n40;
  int i = blockIdx.x * blockDim.x + threadIdx.x;
  if (i < n4) {
    float4 v = ((const float4*)s)[i];
    u16x4 o;
    o[0] = f2bf(v.x); o[1] = f2bf(v.y); o[2] = f2bf(v.z); o[3] = f2bf(v.w);
    ((u16x4*)d)[i] = o;
  }
}

// ---------- batched transpose fp32(1024x1024) -> bf16 transposed ----------
__global__ void tr4(const float* __restrict__ s0, const float* __restrict__ s1,
                    const float* __restrict__ s2, const float* __restrict__ s3,
                    unsigned short* __restrict__ d0, unsigned short* __restrict__ d1,
                    unsigned short* __restrict__ d2, unsigned short* __restrict__ d3) {
  int z = blockIdx.z;
  const float* in = z == 0 ? s0 : (z == 1 ? s1 : (z == 2 ? s2 : s3));
  unsigned short* out = z == 0 ? d0 : (z == 1 ? d1 : (z == 2 ? d2 : d3));
  __shared__ unsigned short s[64][68];
  int t = threadIdx.x;
  int r0 = blockIdx.y * 64, c0 = blockIdx.x * 64;
  int tr = t >> 4, tc4 = (t & 15) * 4;
  for (int i = 0; i < 4; ++i) {
    int r = tr + i * 16;
    float4 v = *(const float4*)(in + (size_t)(r0 + r) * 1024 + c0 + tc4);
    s[r][tc4 + 0] = f2bf(v.x); s[r][tc4 + 1] = f2bf(v.y);
    s[r][tc4 + 2] = f2bf(v.z); s[r][tc4 + 3] = f2bf(v.w);
  }
  __syncthreads();
  for (int i = 0; i < 4; ++i) {
    int oc = tr + i * 16;
    u16x4 o;
    o[0] = s[tc4 + 0][oc]; o[1] = s[tc4 + 1][oc];
    o[2] = s[tc4 + 2][oc]; o[3] = s[tc4 + 3][oc];
    *(u16x4*)(out + (size_t)(c0 + oc) * 1024 + r0 + tc4) = o;
  }
}

// ---------- transpose V: bf16 [4096][1024] -> f16 [1024][4096], kv-permuted ----------
// Column permutation within each 32-col chunk: kv = 32t + s*16 + q*4 + i  ->
// pos = 32t + q*8 + s*4 + i, so one 16B LDS read = A-matching B-frags for 2 kt's.
__global__ void tr_v(const unsigned short* __restrict__ in, unsigned short* __restrict__ out) {
  __shared__ unsigned short s[64][68];
  int t = threadIdx.x;
  int r0 = blockIdx.y * 64, c0 = blockIdx.x * 64;
  int tr = t >> 4, tc4 = (t & 15) * 4;
  for (int i = 0; i < 4; ++i) {
    int r = tr + i * 16;
    u16x4 v = *(const u16x4*)(in + (size_t)(r0 + r) * 1024 + c0 + tc4);
    s[r][tc4 + 0] = v[0]; s[r][tc4 + 1] = v[1]; s[r][tc4 + 2] = v[2]; s[r][tc4 + 3] = v[3];
  }
  __syncthreads();
  for (int i = 0; i < 4; ++i) {
    int oc = tr + i * 16;
    u16x4 o;
#pragma unroll
    for (int j = 0; j < 4; ++j) {
      _Float16 h = (_Float16)bf2f(s[tc4 + j][oc]);
      o[j] = __builtin_bit_cast(unsigned short, h);
    }
    int col = r0 + tc4;                       // kv of first of the 4 consecutive
    int c32 = col & 31;
    int pos = (col & ~31) + ((c32 >> 2) & 3) * 8 + (c32 >> 4) * 4;
    *(u16x4*)(out + (size_t)(c0 + oc) * 4096 + pos) = o;
  }
}

// ---------- NT GEMM: C[M][N] = A[M][K]*B[N][K]^T, 128x128 tile, BK=64, XOR-swizzled LDS ----------
template <bool BF16OUT>
__global__ __launch_bounds__(256) void gemm_nt(
    const unsigned short* __restrict__ A,
    const unsigned short* __restrict__ B0, const unsigned short* __restrict__ B1,
    const unsigned short* __restrict__ B2,
    void* __restrict__ C0, void* __restrict__ C1, void* __restrict__ C2,
    int M, int N, int K) {
  const unsigned short* B = blockIdx.z == 0 ? B0 : (blockIdx.z == 1 ? B1 : B2);
  void* Cv = blockIdx.z == 0 ? C0 : (blockIdx.z == 1 ? C1 : C2);

  __shared__ unsigned short As[128 * 64];
  __shared__ unsigned short Bs[128 * 64];

  int tid = threadIdx.x, w = tid >> 6, lane = tid & 63;
  int lo = lane & 15, quad = lane >> 4;
  int m0 = blockIdx.y * 128, n0 = blockIdx.x * 128;
  int wm = (w >> 1) * 64, wn = (w & 1) * 64;

  f32x4 z4 = {0.f, 0.f, 0.f, 0.f};
  f32x4 acc[4][4];
  for (int mi = 0; mi < 4; ++mi)
    for (int ni = 0; ni < 4; ++ni) acc[mi][ni] = z4;

  int rloc = lane >> 3;
  int srcChunk = (lane & 7) ^ (rloc & 7);
  int cbase = w * 4;
  const unsigned short* Ag = A + (size_t)(m0 + cbase * 8 + rloc) * K + srcChunk * 8;
  const unsigned short* Bg = B + (size_t)(n0 + cbase * 8 + rloc) * K + srcChunk * 8;
  int ldsOfs = cbase * 512 + lane * 8;
  int cx0 = (quad ^ (lane & 7)) * 8;
  int cx1 = ((quad + 4) ^ (lane & 7)) * 8;

  for (int k0 = 0; k0 < K; k0 += 64) {
#pragma unroll
    for (int j = 0; j < 4; ++j) {
      gll16(Ag + (size_t)j * 8 * K + k0, As + ldsOfs + j * 512);
      gll16(Bg + (size_t)j * 8 * K + k0, Bs + ldsOfs + j * 512);
    }
    __syncthreads();
#pragma unroll
    for (int ks = 0; ks < 2; ++ks) {
      int cx = ks ? cx1 : cx0;
      bf16x8 af[4], bfr[4];
#pragma unroll
      for (int mi = 0; mi < 4; ++mi)
        af[mi] = *(const bf16x8*)(As + (wm + mi * 16 + lo) * 64 + cx);
#pragma unroll
      for (int ni = 0; ni < 4; ++ni)
        bfr[ni] = *(const bf16x8*)(Bs + (wn + ni * 16 + lo) * 64 + cx);
#pragma unroll
      for (int mi = 0; mi < 4; ++mi)
#pragma unroll
        for (int ni = 0; ni < 4; ++ni)
          acc[mi][ni] = __builtin_amdgcn_mfma_f32_16x16x32_bf16(af[mi], bfr[ni], acc[mi][ni], 0, 0, 0);
    }
    __syncthreads();
  }

#pragma unroll
  for (int mi = 0; mi < 4; ++mi)
#pragma unroll
    for (int ni = 0; ni < 4; ++ni)
      for (int i = 0; i < 4; ++i) {
        int r = m0 + wm + mi * 16 + quad * 4 + i;
        int c = n0 + wn + ni * 16 + lo;
        if (BF16OUT)
          ((unsigned short*)Cv)[(size_t)r * N + c] = f2bf(acc[mi][ni][i]);
        else
          ((float*)Cv)[(size_t)r * N + c] = acc[mi][ni][i];
      }
}

// ---------- flash attention v8: all-b128 LDS reads, conflict-free ----------
// Q,K: bf16 [4096][1024]; Vt: f16 [1024][4096] kv-permuted; O: bf16 [4096][1024].
// 1D grid 1024 blocks x 256 thr; id%8 fixed per (b,h) for XCD-local K/V.
// LDS double-buffer, prefetch-after-barrier, single barrier per KV tile.
__global__ __launch_bounds__(256, 4) void flash_attn(
    const unsigned short* __restrict__ Q, const unsigned short* __restrict__ Kg_,
    const unsigned short* __restrict__ Vt, const float* __restrict__ ent,
    unsigned short* __restrict__ O) {
  int tid = threadIdx.x, w = tid >> 6, lane = tid & 63;
  int lo = lane & 15, quad = lane >> 4;

  int bid = blockIdx.x;
  int g = (bid & 7) + 8 * (bid >> 8);        // (b,h) group: id%8 fixed per group
  int qt = (bid >> 3) & 31;                  // q-tile within group
  int b = g >> 4, h = g & 15;
  int q0 = qt * 64;
  float scale = ent[h] * (0.125f * LOG2E);

  __shared__ unsigned short Ks[2][64 * 64];
  __shared__ unsigned short Vts[2][64 * 64];   // f16 bits, [d][kv-permuted], swizzled

  // Q fragments (B-operand of S^T) straight from global, scale folded in. 16 q rows/wave.
  bf16x8 aq[2];
#pragma unroll
  for (int ks = 0; ks < 2; ++ks) {
    uint4 v = *(const uint4*)(Q + (size_t)(b * 2048 + q0 + w * 16 + lo) * 1024 +
                              h * 64 + ks * 32 + quad * 8);
    unsigned int* pv = (unsigned int*)&v;
    uint4 o; unsigned int* po = (unsigned int*)&o;
#pragma unroll
    for (int j = 0; j < 4; ++j) {
      float f0 = bf2f((unsigned short)(pv[j] & 0xffffu)) * scale;
      float f1 = bf2f((unsigned short)(pv[j] >> 16)) * scale;
      po[j] = (unsigned int)f2bf(f0) | ((unsigned int)f2bf(f1) << 16);
    }
    aq[ks] = *(bf16x8*)&o;
  }

  f32x4 binit = {-PBIAS, -PBIAS, -PBIAS, -PBIAS};
  f32x4 z4 = {0.f, 0.f, 0.f, 0.f};
  f32x4 acco[4];
#pragma unroll
  for (int di = 0; di < 4; ++di) acco[di] = z4;
  float lsum = 0.f;

  int rloc = lane >> 3;
  int srcChunk = (lane & 7) ^ (rloc & 7);
  int cb = w * 2;                            // 4 waves cover 8 chunks per matrix
  const unsigned short* Kp = Kg_ + (size_t)(b * 2048) * 1024 + h * 64;
  const unsigned short* Vp = Vt + (size_t)(h * 64) * 4096 + (size_t)b * 2048;
  int cx0 = (quad ^ (lane & 7)) * 8;
  int cx1 = ((quad + 4) ^ (lane & 7)) * 8;

  // stage tile 0 into buffer 0
#pragma unroll
  for (int j = 0; j < 2; ++j) {
    int c = cb + j;
    int r = c * 8 + rloc;
    gll16(Kp + (size_t)r * 1024 + srcChunk * 8, Ks[0] + c * 512 + lane * 8);
    gll16(Vp + (size_t)r * 4096 + srcChunk * 8, Vts[0] + c * 512 + lane * 8);
  }

  for (int it = 0; it < 32; ++it) {
    int buf = it & 1;
    __syncthreads();   // drains this tile's staging (issued one full tile ago)
    if (it + 1 < 32) {
      int kvn = (it + 1) * 64;
#pragma unroll
      for (int j = 0; j < 2; ++j) {
        int c = cb + j;
        int r = c * 8 + rloc;
        gll16(Kp + (size_t)(kvn + r) * 1024 + srcChunk * 8, Ks[buf ^ 1] + c * 512 + lane * 8);
        gll16(Vp + (size_t)r * 4096 + kvn + srcChunk * 8, Vts[buf ^ 1] + c * 512 + lane * 8);
      }
    }
    const unsigned short* Kb_ = Ks[buf];
    const unsigned short* Vb_ = Vts[buf];

    // S^T = K.Q^T : C[m=kv][n=q]; bias -PBIAS folded into the C-init (free)
    f32x4 accs[4];
#pragma unroll
    for (int kt = 0; kt < 4; ++kt) {
      bf16x8 kf0 = *(const bf16x8*)(Kb_ + (kt * 16 + lo) * 64 + cx0);
      bf16x8 kf1 = *(const bf16x8*)(Kb_ + (kt * 16 + lo) * 64 + cx1);
      f32x4 a = __builtin_amdgcn_mfma_f32_16x16x32_bf16(kf0, aq[0], binit, 0, 0, 0);
      accs[kt] = __builtin_amdgcn_mfma_f32_16x16x32_bf16(kf1, aq[1], a, 0, 0, 0);
    }

    // P' = 2^(S^T - bias): registers hold P[q=lo][kv] == f16 A-frag layout (K=16)
    f16x4 ap[4];
#pragma unroll
    for (int kt = 0; kt < 4; ++kt) {
      float p0 = exp2f(accs[kt][0]);
      float p1 = exp2f(accs[kt][1]);
      float p2 = exp2f(accs[kt][2]);
      float p3 = exp2f(accs[kt][3]);
      lsum += (p0 + p1) + (p2 + p3);
      u32x2 uu;
      uu[0] = __builtin_bit_cast(unsigned int, __builtin_amdgcn_cvt_pkrtz(p0, p1));
      uu[1] = __builtin_bit_cast(unsigned int, __builtin_amdgcn_cvt_pkrtz(p2, p3));
      ap[kt] = __builtin_bit_cast(f16x4, uu);
    }

    // O += P.V via f16 16x16x16 MFMA; one b128 per (t2,di) feeds kt=2*t2 and 2*t2+1
    // (kv-permuted Vt: 16B chunk 4*t2+quad = {32*t2+quad*4+i} ++ {32*t2+16+quad*4+i})
#pragma unroll
    for (int t2 = 0; t2 < 2; ++t2)
#pragma unroll
      for (int di = 0; di < 4; ++di) {
        f16x8 bv8 = *(const f16x8*)(Vb_ + (di * 16 + lo) * 64 +
                                    (((t2 * 4 + quad) ^ (lo & 7)) << 3));
        f16x4 b0 = __builtin_shufflevector(bv8, bv8, 0, 1, 2, 3);
        f16x4 b1 = __builtin_shufflevector(bv8, bv8, 4, 5, 6, 7);
        acco[di] = __builtin_amdgcn_mfma_f32_16x16x16f16(ap[2 * t2], b0, acco[di], 0, 0, 0);
        acco[di] = __builtin_amdgcn_mfma_f32_16x16x16f16(ap[2 * t2 + 1], b1, acco[di], 0, 0, 0);
      }
  }

  // row sum for q=lo spread over quads -> 2 shuffles
  float v = lsum;
  v += __shfl_xor(v, 16);
  v += __shfl_xor(v, 32);
  float inv = 1.0f / v;

  // O is C-layout (row=q=quad*4+i, col=d=di*16+lo); fetch inv for q=quad*4+i via shuffle
#pragma unroll
  for (int i = 0; i < 4; ++i) {
    float invq = __shfl(inv, quad * 4 + i);
#pragma unroll
    for (int di = 0; di < 4; ++di) {
      size_t ofs = (size_t)(b * 2048 + q0 + w * 16 + quad * 4 + i) * 1024 +
                   h * 64 + di * 16 + lo;
      O[ofs] = f2bf(acco[di][i] * invq);
    }
  }
}

// ---------- launch ----------
extern "C" void kernel_launch(void* const* d_in, const int* in_sizes, int n_in,
                              void* d_out, int out_size, void* d_ws, size_t ws_size,
                              hipStream_t stream) {
  const float* x   = (const float*)d_in[0];
  const float* R   = (const float*)d_in[1];
  const float* ent = (const float*)d_in[2];
  const float* Wq  = (const float*)d_in[3];
  const float* Wk  = (const float*)d_in[4];
  const float* Wv  = (const float*)d_in[5];
  const float* Wo  = (const float*)d_in[6];
  float* out = (float*)d_out;

  const size_t MLD = (size_t)4096 * 1024;
  const size_t DD  = (size_t)1024 * 1024;
  if (ws_size < (MLD * 6 + DD * 8) * 2) return;

  unsigned short* ws  = (unsigned short*)d_ws;
  unsigned short* xb  = ws;
  unsigned short* RT  = xb + MLD;
  unsigned short* WqT = RT + DD;
  unsigned short* WkT = WqT + DD;
  unsigned short* WvT = WkT + DD;
  unsigned short* Wob = WvT + DD;
  unsigned short* AqT = Wob + DD;
  unsigned short* AkT = AqT + DD;
  unsigned short* AvT = AkT + DD;
  unsigned short* Qb  = AvT + DD;
  unsigned short* Kb  = Qb + MLD;
  unsigned short* Vb  = Kb + MLD;
  unsigned short* Vtf = Vb + MLD;   // V^T as f16 [1024][4096], kv-permuted
  unsigned short* aO  = Vtf + MLD;

  cvt2<<<dim3(4096, 2), dim3(256), 0, stream>>>(
      x, xb, (int)(MLD / 4), Wo, Wob, (int)(DD / 4));
  tr4<<<dim3(16, 16, 4), dim3(256), 0, stream>>>(R, Wq, Wk, Wv, RT, WqT, WkT, WvT);

  // A*T = NT(RT, W*T) = R^T W* = (W*^T R)^T
  gemm_nt<true><<<dim3(8, 8, 3), dim3(256), 0, stream>>>(
      RT, WqT, WkT, WvT, (void*)AqT, (void*)AkT, (void*)AvT, 1024, 1024, 1024);
  // Q/K/V = NT(xb, A*T)
  gemm_nt<true><<<dim3(8, 32, 3), dim3(256), 0, stream>>>(
      xb, AqT, AkT, AvT, (void*)Qb, (void*)Kb, (void*)Vb, 4096, 1024, 1024);
  // V -> V^T (f16, kv-permuted)
  tr_v<<<dim3(16, 64), dim3(256), 0, stream>>>(Vb, Vtf);
  // attention
  flash_attn<<<dim3(1024), dim3(256), 0, stream>>>(Qb, Kb, Vtf, ent, aO);
  // out = NT(aO, Wob) -> fp32
  gemm_nt<false><<<dim3(8, 32, 1), dim3(256), 0, stream>>>(
      aO, Wob, Wob, Wob, (void*)out, (void*)out, (void*)out, 4096, 1024, 1024);
}

// Round 10
// 214.674 us; speedup vs baseline: 1.5755x; 1.0903x over previous
//
#include <hip/hip_runtime.h>
#include <cstdint>
#include <cstddef>

// ---------- types ----------
typedef __attribute__((ext_vector_type(8))) short  bf16x8;   // MFMA bf16 A/B frag (K=32)
typedef __attribute__((ext_vector_type(8))) _Float16 f16x8;  // 16B LDS read (2 f16 B-frags)
typedef __attribute__((ext_vector_type(4))) _Float16 f16x4;  // MFMA f16 A/B frag (K=16)
typedef __attribute__((ext_vector_type(4))) float  f32x4;    // MFMA C/D frag
typedef __attribute__((ext_vector_type(4))) unsigned short u16x4;
typedef __attribute__((ext_vector_type(2))) unsigned int u32x2;

#define LOG2E 1.44269504088896340736f
#define PBIAS 6.0f   // softmax shift (cancels in normalization); keeps 2^t in f16 range

__device__ __forceinline__ unsigned short f2bf(float f) {
  unsigned int u = __builtin_bit_cast(unsigned int, f);
  u += 0x7fffu + ((u >> 16) & 1u);
  return (unsigned short)(u >> 16);
}
__device__ __forceinline__ float bf2f(unsigned short s) {
  unsigned int u = ((unsigned int)s) << 16;
  return __builtin_bit_cast(float, u);
}

// single v_exp_f32 via compiler intrinsic (hazards handled; inputs bounded here)
__device__ __forceinline__ float fast_exp2(float x) {
  return __builtin_amdgcn_exp2f(x);
}

// async global->LDS, 16B per lane (wave-uniform LDS base + lane*16)
__device__ __forceinline__ void gll16(const void* g, void* l) {
  __builtin_amdgcn_global_load_lds(
      (const __attribute__((address_space(1))) unsigned int*)g,
      (__attribute__((address_space(3))) unsigned int*)l, 16, 0, 0);
}

// ---------- fused prep: cvt x (blk<4096), cvt Wo (<5120), 4x transpose (<6144) ----------
__global__ __launch_bounds__(256) void prep(
    const float* __restrict__ x,  unsigned short* __restrict__ xb,
    const float* __restrict__ Wo, unsigned short* __restrict__ Wob,
    const float* __restrict__ R,  const float* __restrict__ Wq,
    const float* __restrict__ Wk, const float* __restrict__ Wv,
    unsigned short* __restrict__ RT,  unsigned short* __restrict__ WqT,
    unsigned short* __restrict__ WkT, unsigned short* __restrict__ WvT) {
  int bid = blockIdx.x;
  __shared__ unsigned short s[64][68];
  if (bid < 5120) {
    const float* src = bid < 4096 ? x : Wo;
    unsigned short* dst = bid < 4096 ? xb : Wob;
    int i = (bid < 4096 ? bid : bid - 4096) * 256 + threadIdx.x;
    float4 v = ((const float4*)src)[i];
    u16x4 o;
    o[0] = f2bf(v.x); o[1] = f2bf(v.y); o[2] = f2bf(v.z); o[3] = f2bf(v.w);
    ((u16x4*)dst)[i] = o;
    return;
  }
  int t = bid - 5120;
  int z = t >> 8, tile = t & 255;
  const float* in = z == 0 ? R : (z == 1 ? Wq : (z == 2 ? Wk : Wv));
  unsigned short* out = z == 0 ? RT : (z == 1 ? WqT : (z == 2 ? WkT : WvT));
  int r0 = (tile >> 4) * 64, c0 = (tile & 15) * 64;
  int tt = threadIdx.x;
  int tr = tt >> 4, tc4 = (tt & 15) * 4;
  for (int i = 0; i < 4; ++i) {
    int r = tr + i * 16;
    float4 v = *(const float4*)(in + (size_t)(r0 + r) * 1024 + c0 + tc4);
    s[r][tc4 + 0] = f2bf(v.x); s[r][tc4 + 1] = f2bf(v.y);
    s[r][tc4 + 2] = f2bf(v.z); s[r][tc4 + 3] = f2bf(v.w);
  }
  __syncthreads();
  for (int i = 0; i < 4; ++i) {
    int oc = tr + i * 16;
    u16x4 o;
    o[0] = s[tc4 + 0][oc]; o[1] = s[tc4 + 1][oc];
    o[2] = s[tc4 + 2][oc]; o[3] = s[tc4 + 3][oc];
    *(u16x4*)(out + (size_t)(c0 + oc) * 1024 + r0 + tc4) = o;
  }
}

// ---------- transpose V: bf16 [4096][1024] -> f16 [1024][4096], kv-permuted ----------
// Column permutation within each 32-col chunk: kv = 32t + s*16 + q*4 + i  ->
// pos = 32t + q*8 + s*4 + i, so one 16B LDS read = A-matching B-frags for 2 kt's.
__global__ void tr_v(const unsigned short* __restrict__ in, unsigned short* __restrict__ out) {
  __shared__ unsigned short s[64][68];
  int t = threadIdx.x;
  int r0 = blockIdx.y * 64, c0 = blockIdx.x * 64;
  int tr = t >> 4, tc4 = (t & 15) * 4;
  for (int i = 0; i < 4; ++i) {
    int r = tr + i * 16;
    u16x4 v = *(const u16x4*)(in + (size_t)(r0 + r) * 1024 + c0 + tc4);
    s[r][tc4 + 0] = v[0]; s[r][tc4 + 1] = v[1]; s[r][tc4 + 2] = v[2]; s[r][tc4 + 3] = v[3];
  }
  __syncthreads();
  for (int i = 0; i < 4; ++i) {
    int oc = tr + i * 16;
    u16x4 o;
#pragma unroll
    for (int j = 0; j < 4; ++j) {
      _Float16 h = (_Float16)bf2f(s[tc4 + j][oc]);
      o[j] = __builtin_bit_cast(unsigned short, h);
    }
    int col = r0 + tc4;                       // kv of first of the 4 consecutive
    int c32 = col & 31;
    int pos = (col & ~31) + ((c32 >> 2) & 3) * 8 + (c32 >> 4) * 4;
    *(u16x4*)(out + (size_t)(c0 + oc) * 4096 + pos) = o;
  }
}

// ---------- NT GEMM: C[M][N] = A[M][K]*B[N][K]^T, 128x128 tile, BK=64, XOR-swizzled LDS ----------
template <bool BF16OUT>
__global__ __launch_bounds__(256) void gemm_nt(
    const unsigned short* __restrict__ A,
    const unsigned short* __restrict__ B0, const unsigned short* __restrict__ B1,
    const unsigned short* __restrict__ B2,
    void* __restrict__ C0, void* __restrict__ C1, void* __restrict__ C2,
    int M, int N, int K) {
  const unsigned short* B = blockIdx.z == 0 ? B0 : (blockIdx.z == 1 ? B1 : B2);
  void* Cv = blockIdx.z == 0 ? C0 : (blockIdx.z == 1 ? C1 : C2);

  __shared__ unsigned short As[128 * 64];
  __shared__ unsigned short Bs[128 * 64];

  int tid = threadIdx.x, w = tid >> 6, lane = tid & 63;
  int lo = lane & 15, quad = lane >> 4;
  int m0 = blockIdx.y * 128, n0 = blockIdx.x * 128;
  int wm = (w >> 1) * 64, wn = (w & 1) * 64;

  f32x4 z4 = {0.f, 0.f, 0.f, 0.f};
  f32x4 acc[4][4];
  for (int mi = 0; mi < 4; ++mi)
    for (int ni = 0; ni < 4; ++ni) acc[mi][ni] = z4;

  int rloc = lane >> 3;
  int srcChunk = (lane & 7) ^ (rloc & 7);
  int cbase = w * 4;
  const unsigned short* Ag = A + (size_t)(m0 + cbase * 8 + rloc) * K + srcChunk * 8;
  const unsigned short* Bg = B + (size_t)(n0 + cbase * 8 + rloc) * K + srcChunk * 8;
  int ldsOfs = cbase * 512 + lane * 8;
  int cx0 = (quad ^ (lane & 7)) * 8;
  int cx1 = ((quad + 4) ^ (lane & 7)) * 8;

  for (int k0 = 0; k0 < K; k0 += 64) {
#pragma unroll
    for (int j = 0; j < 4; ++j) {
      gll16(Ag + (size_t)j * 8 * K + k0, As + ldsOfs + j * 512);
      gll16(Bg + (size_t)j * 8 * K + k0, Bs + ldsOfs + j * 512);
    }
    __syncthreads();
#pragma unroll
    for (int ks = 0; ks < 2; ++ks) {
      int cx = ks ? cx1 : cx0;
      bf16x8 af[4], bfr[4];
#pragma unroll
      for (int mi = 0; mi < 4; ++mi)
        af[mi] = *(const bf16x8*)(As + (wm + mi * 16 + lo) * 64 + cx);
#pragma unroll
      for (int ni = 0; ni < 4; ++ni)
        bfr[ni] = *(const bf16x8*)(Bs + (wn + ni * 16 + lo) * 64 + cx);
#pragma unroll
      for (int mi = 0; mi < 4; ++mi)
#pragma unroll
        for (int ni = 0; ni < 4; ++ni)
          acc[mi][ni] = __builtin_amdgcn_mfma_f32_16x16x32_bf16(af[mi], bfr[ni], acc[mi][ni], 0, 0, 0);
    }
    __syncthreads();
  }

#pragma unroll
  for (int mi = 0; mi < 4; ++mi)
#pragma unroll
    for (int ni = 0; ni < 4; ++ni)
      for (int i = 0; i < 4; ++i) {
        int r = m0 + wm + mi * 16 + quad * 4 + i;
        int c = n0 + wn + ni * 16 + lo;
        if (BF16OUT)
          ((unsigned short*)Cv)[(size_t)r * N + c] = f2bf(acc[mi][ni][i]);
        else
          ((float*)Cv)[(size_t)r * N + c] = acc[mi][ni][i];
      }
}

// ---------- flash attention v10: v8 + intrinsic exp2 ----------
// Q,K: bf16 [4096][1024]; Vt: f16 [1024][4096] kv-permuted; O: bf16 [4096][1024].
// 1D grid 1024 blocks x 256 thr; id%8 fixed per (b,h) for XCD-local K/V.
// LDS double-buffer, prefetch-after-barrier, single barrier per KV tile.
__global__ __launch_bounds__(256, 4) void flash_attn(
    const unsigned short* __restrict__ Q, const unsigned short* __restrict__ Kg_,
    const unsigned short* __restrict__ Vt, const float* __restrict__ ent,
    unsigned short* __restrict__ O) {
  int tid = threadIdx.x, w = tid >> 6, lane = tid & 63;
  int lo = lane & 15, quad = lane >> 4;

  int bid = blockIdx.x;
  int g = (bid & 7) + 8 * (bid >> 8);        // (b,h) group: id%8 fixed per group
  int qt = (bid >> 3) & 31;                  // q-tile within group
  int b = g >> 4, h = g & 15;
  int q0 = qt * 64;
  float scale = ent[h] * (0.125f * LOG2E);

  __shared__ unsigned short Ks[2][64 * 64];
  __shared__ unsigned short Vts[2][64 * 64];   // f16 bits, [d][kv-permuted], swizzled

  // Q fragments (B-operand of S^T) straight from global, scale folded in. 16 q rows/wave.
  bf16x8 aq[2];
#pragma unroll
  for (int ks = 0; ks < 2; ++ks) {
    uint4 v = *(const uint4*)(Q + (size_t)(b * 2048 + q0 + w * 16 + lo) * 1024 +
                              h * 64 + ks * 32 + quad * 8);
    unsigned int* pv = (unsigned int*)&v;
    uint4 o; unsigned int* po = (unsigned int*)&o;
#pragma unroll
    for (int j = 0; j < 4; ++j) {
      float f0 = bf2f((unsigned short)(pv[j] & 0xffffu)) * scale;
      float f1 = bf2f((unsigned short)(pv[j] >> 16)) * scale;
      po[j] = (unsigned int)f2bf(f0) | ((unsigned int)f2bf(f1) << 16);
    }
    aq[ks] = *(bf16x8*)&o;
  }

  f32x4 binit = {-PBIAS, -PBIAS, -PBIAS, -PBIAS};
  f32x4 z4 = {0.f, 0.f, 0.f, 0.f};
  f32x4 acco[4];
#pragma unroll
  for (int di = 0; di < 4; ++di) acco[di] = z4;
  float lsum = 0.f;

  int rloc = lane >> 3;
  int srcChunk = (lane & 7) ^ (rloc & 7);
  int cb = w * 2;                            // 4 waves cover 8 chunks per matrix
  const unsigned short* Kp = Kg_ + (size_t)(b * 2048) * 1024 + h * 64;
  const unsigned short* Vp = Vt + (size_t)(h * 64) * 4096 + (size_t)b * 2048;
  int cx0 = (quad ^ (lane & 7)) * 8;
  int cx1 = ((quad + 4) ^ (lane & 7)) * 8;

  // stage tile 0 into buffer 0
#pragma unroll
  for (int j = 0; j < 2; ++j) {
    int c = cb + j;
    int r = c * 8 + rloc;
    gll16(Kp + (size_t)r * 1024 + srcChunk * 8, Ks[0] + c * 512 + lane * 8);
    gll16(Vp + (size_t)r * 4096 + srcChunk * 8, Vts[0] + c * 512 + lane * 8);
  }

  for (int it = 0; it < 32; ++it) {
    int buf = it & 1;
    __syncthreads();   // drains this tile's staging (issued one full tile ago)
    if (it + 1 < 32) {
      int kvn = (it + 1) * 64;
#pragma unroll
      for (int j = 0; j < 2; ++j) {
        int c = cb + j;
        int r = c * 8 + rloc;
        gll16(Kp + (size_t)(kvn + r) * 1024 + srcChunk * 8, Ks[buf ^ 1] + c * 512 + lane * 8);
        gll16(Vp + (size_t)r * 4096 + kvn + srcChunk * 8, Vts[buf ^ 1] + c * 512 + lane * 8);
      }
    }
    const unsigned short* Kb_ = Ks[buf];
    const unsigned short* Vb_ = Vts[buf];

    // S^T = K.Q^T : C[m=kv][n=q]; bias -PBIAS folded into the C-init (free)
    f32x4 accs[4];
#pragma unroll
    for (int kt = 0; kt < 4; ++kt) {
      bf16x8 kf0 = *(const bf16x8*)(Kb_ + (kt * 16 + lo) * 64 + cx0);
      bf16x8 kf1 = *(const bf16x8*)(Kb_ + (kt * 16 + lo) * 64 + cx1);
      f32x4 a = __builtin_amdgcn_mfma_f32_16x16x32_bf16(kf0, aq[0], binit, 0, 0, 0);
      accs[kt] = __builtin_amdgcn_mfma_f32_16x16x32_bf16(kf1, aq[1], a, 0, 0, 0);
    }

    // P' = 2^(S^T - bias): registers hold P[q=lo][kv] == f16 A-frag layout (K=16)
    f16x4 ap[4];
#pragma unroll
    for (int kt = 0; kt < 4; ++kt) {
      float p0 = fast_exp2(accs[kt][0]);
      float p1 = fast_exp2(accs[kt][1]);
      float p2 = fast_exp2(accs[kt][2]);
      float p3 = fast_exp2(accs[kt][3]);
      lsum += (p0 + p1) + (p2 + p3);
      u32x2 uu;
      uu[0] = __builtin_bit_cast(unsigned int, __builtin_amdgcn_cvt_pkrtz(p0, p1));
      uu[1] = __builtin_bit_cast(unsigned int, __builtin_amdgcn_cvt_pkrtz(p2, p3));
      ap[kt] = __builtin_bit_cast(f16x4, uu);
    }

    // O += P.V via f16 16x16x16 MFMA; one b128 per (t2,di) feeds kt=2*t2 and 2*t2+1
    // (kv-permuted Vt: 16B chunk 4*t2+quad = {32*t2+quad*4+i} ++ {32*t2+16+quad*4+i})
#pragma unroll
    for (int t2 = 0; t2 < 2; ++t2)
#pragma unroll
      for (int di = 0; di < 4; ++di) {
        f16x8 bv8 = *(const f16x8*)(Vb_ + (di * 16 + lo) * 64 +
                                    (((t2 * 4 + quad) ^ (lo & 7)) << 3));
        f16x4 b0 = __builtin_shufflevector(bv8, bv8, 0, 1, 2, 3);
        f16x4 b1 = __builtin_shufflevector(bv8, bv8, 4, 5, 6, 7);
        acco[di] = __builtin_amdgcn_mfma_f32_16x16x16f16(ap[2 * t2], b0, acco[di], 0, 0, 0);
        acco[di] = __builtin_amdgcn_mfma_f32_16x16x16f16(ap[2 * t2 + 1], b1, acco[di], 0, 0, 0);
      }
  }

  // row sum for q=lo spread over quads -> 2 shuffles
  float v = lsum;
  v += __shfl_xor(v, 16);
  v += __shfl_xor(v, 32);
  float inv = 1.0f / v;

  // O is C-layout (row=q=quad*4+i, col=d=di*16+lo); fetch inv for q=quad*4+i via shuffle
#pragma unroll
  for (int i = 0; i < 4; ++i) {
    float invq = __shfl(inv, quad * 4 + i);
#pragma unroll
    for (int di = 0; di < 4; ++di) {
      size_t ofs = (size_t)(b * 2048 + q0 + w * 16 + quad * 4 + i) * 1024 +
                   h * 64 + di * 16 + lo;
      O[ofs] = f2bf(acco[di][i] * invq);
    }
  }
}

// ---------- launch ----------
extern "C" void kernel_launch(void* const* d_in, const int* in_sizes, int n_in,
                              void* d_out, int out_size, void* d_ws, size_t ws_size,
                              hipStream_t stream) {
  const float* x   = (const float*)d_in[0];
  const float* R   = (const float*)d_in[1];
  const float* ent = (const float*)d_in[2];
  const float* Wq  = (const float*)d_in[3];
  const float* Wk  = (const float*)d_in[4];
  const float* Wv  = (const float*)d_in[5];
  const float* Wo  = (const float*)d_in[6];
  float* out = (float*)d_out;

  const size_t MLD = (size_t)4096 * 1024;
  const size_t DD  = (size_t)1024 * 1024;
  if (ws_size < (MLD * 6 + DD * 8) * 2) return;

  unsigned short* ws  = (unsigned short*)d_ws;
  unsigned short* xb  = ws;
  unsigned short* RT  = xb + MLD;
  unsigned short* WqT = RT + DD;
  unsigned short* WkT = WqT + DD;
  unsigned short* WvT = WkT + DD;
  unsigned short* Wob = WvT + DD;
  unsigned short* AqT = Wob + DD;
  unsigned short* AkT = AqT + DD;
  unsigned short* AvT = AkT + DD;
  unsigned short* Qb  = AvT + DD;
  unsigned short* Kb  = Qb + MLD;
  unsigned short* Vb  = Kb + MLD;
  unsigned short* Vtf = Vb + MLD;   // V^T as f16 [1024][4096], kv-permuted
  unsigned short* aO  = Vtf + MLD;

  // fused converts + weight transposes (one launch)
  prep<<<dim3(6144), dim3(256), 0, stream>>>(
      x, xb, Wo, Wob, R, Wq, Wk, Wv, RT, WqT, WkT, WvT);

  // A*T = NT(RT, W*T) = R^T W* = (W*^T R)^T
  gemm_nt<true><<<dim3(8, 8, 3), dim3(256), 0, stream>>>(
      RT, WqT, WkT, WvT, (void*)AqT, (void*)AkT, (void*)AvT, 1024, 1024, 1024);
  // Q/K/V = NT(xb, A*T)
  gemm_nt<true><<<dim3(8, 32, 3), dim3(256), 0, stream>>>(
      xb, AqT, AkT, AvT, (void*)Qb, (void*)Kb, (void*)Vb, 4096, 1024, 1024);
  // V -> V^T (f16, kv-permuted)
  tr_v<<<dim3(16, 64), dim3(256), 0, stream>>>(Vb, Vtf);
  // attention
  flash_attn<<<dim3(1024), dim3(256), 0, stream>>>(Qb, Kb, Vtf, ent, aO);
  // out = NT(aO, Wob) -> fp32
  gemm_nt<false><<<dim3(8, 32, 1), dim3(256), 0, stream>>>(
      aO, Wob, Wob, Wob, (void*)out, (void*)out, (void*)out, 4096, 1024, 1024);
}